// Round 7
// baseline (424.863 us; speedup 1.0000x reference)
//
#include <hip/hip_runtime.h>
#include <hip/hip_bf16.h>

#define N_NODES 100000
#define N_EDGES 1600000
#define NB 391        // bins of 256 dst-nodes
#define CAP 4608      // per-bin capacity: mean 4092, sigma 64 -> +8 sigma
#define CHUNK 8192    // edges per binfill block

__device__ __forceinline__ float bcast_lane(float v, int k) {
    return __int_as_float(__builtin_amdgcn_readlane(__float_as_int(v), k));
}

// ---------------- phase 1: bin edges by dst>>8 ----------------

__global__ void __launch_bounds__(1024) binfill_kernel(
        const int* __restrict__ src, const int* __restrict__ dst,
        int* __restrict__ bincur, unsigned* __restrict__ binned, int e) {
    __shared__ int hcount[NB];
    __shared__ int hloc[NB];
    __shared__ int hbase[NB];
    __shared__ unsigned stage[CHUNK];

    int tid = threadIdx.x;
    int base0 = blockIdx.x * CHUNK;

    for (int i = tid; i < NB; i += 1024) hcount[i] = 0;
    __syncthreads();

    int bq[8]; int rq[8]; unsigned pq[8];
    #pragma unroll
    for (int q = 0; q < 8; ++q) {
        int i = base0 + q * 1024 + tid;
        bq[q] = -1;
        if (i < e) {
            int s = src[i], d = dst[i];
            int b = d >> 8;
            bq[q] = b;
            rq[q] = atomicAdd(&hcount[b], 1);
            pq[q] = ((unsigned)s << 8) | (unsigned)(d & 255);
        }
    }
    __syncthreads();

    if (tid < NB) hbase[tid] = atomicAdd(&bincur[tid], hcount[tid]);

    if (tid < 64) {
        int run = 0;
        for (int seg = 0; seg < NB; seg += 64) {
            int idx = seg + tid;
            int d0 = (idx < NB) ? hcount[idx] : 0;
            int v = d0;
            #pragma unroll
            for (int off = 1; off < 64; off <<= 1) {
                int t = __shfl_up(v, off);
                if (tid >= off) v += t;
            }
            if (idx < NB) hloc[idx] = run + v - d0;
            run += __shfl(v, 63);
        }
    }
    __syncthreads();

    #pragma unroll
    for (int q = 0; q < 8; ++q)
        if (bq[q] >= 0) stage[hloc[bq[q]] + rq[q]] = pq[q];
    __syncthreads();

    int w = tid >> 6, lane = tid & 63;
    for (int b = w; b < NB; b += 16) {
        int len = hcount[b];
        int gb0 = hbase[b];
        int lim = min(len, CAP - gb0);
        int lo = hloc[b];
        unsigned* gp = binned + (long long)b * CAP + gb0;
        for (int j = lane; j < lim; j += 64) gp[j] = stage[lo + j];
    }
}

// ---------------- phase 2: scan bin totals ----------------

__global__ void binscan_kernel(const int* __restrict__ bincur,
                               int* __restrict__ binbase, int* __restrict__ row_off) {
    int lane = threadIdx.x;   // 64 threads
    int run = 0;
    for (int seg = 0; seg < NB; seg += 64) {
        int idx = seg + lane;
        int d = (idx < NB) ? bincur[idx] : 0;
        int v = d;
        #pragma unroll
        for (int off = 1; off < 64; off <<= 1) {
            int t = __shfl_up(v, off);
            if (lane >= off) v += t;
        }
        if (idx < NB) binbase[idx] = run + v - d;
        run += __shfl(v, 63);
    }
    if (lane == 0) row_off[N_NODES] = run;
}

// ---------------- phase 3: per-bin CSR finalize ----------------

__global__ void __launch_bounds__(256) csrfinal_kernel(
        const unsigned* __restrict__ binned, const int* __restrict__ bincur,
        const int* __restrict__ binbase,
        int* __restrict__ row_off, int* __restrict__ src_sorted) {
    __shared__ int cnt[256];
    __shared__ int wsum[4];
    __shared__ unsigned stage[CAP];
    int b = blockIdx.x, tid = threadIdx.x, lane = tid & 63, w = tid >> 6;
    long long boff = (long long)b * CAP;
    int total = min(bincur[b], CAP);
    int base = binbase[b];

    cnt[tid] = 0;
    __syncthreads();
    for (int j = tid; j < total; j += 256) atomicAdd(&cnt[binned[boff + j] & 255u], 1);
    __syncthreads();

    int d = cnt[tid];
    int v = d;
    #pragma unroll
    for (int off = 1; off < 64; off <<= 1) {
        int t = __shfl_up(v, off);
        if (lane >= off) v += t;
    }
    if (lane == 63) wsum[w] = v;
    __syncthreads();
    int woff = 0;
    for (int ww = 0; ww < w; ++ww) woff += wsum[ww];
    int excl = woff + v - d;

    int node = b * 256 + tid;
    if (node < N_NODES) row_off[node] = base + excl;
    __syncthreads();
    cnt[tid] = excl;          // cursor
    __syncthreads();

    for (int j = tid; j < total; j += 256) {
        unsigned p = binned[boff + j];
        int pos = atomicAdd(&cnt[p & 255u], 1);
        stage[pos] = p >> 8;
    }
    __syncthreads();
    for (int j = tid; j < total; j += 256) src_sorted[base + j] = (int)stage[j];
}

// ---------------- fused layer: mean-aggregate + dual matvec + relu ----------
// one wave per node (grid-stride, ~16 nodes/wave at 1536 blocks).
// Gather: 4 edges x 16 lanes x float4. Weights in VGPRs (lane = out channel).
// k-loop uses 8 independent fma chains (aA[4]+aH[4], static-indexed) so it is
// issue-bound, not dep-latency-bound. Grid 1536 blocks -> 24 waves/CU at
// VGPR=84 (R6 evidence: grid of 768 capped occupancy at 29%).

template <bool LAST>
__global__ void __launch_bounds__(256) fused64_kernel(
        const float* __restrict__ xin, const int* __restrict__ row_off,
        const int* __restrict__ src_sorted,
        const float* __restrict__ w_l, const float* __restrict__ bvec,
        const float* __restrict__ w_r,
        const float* __restrict__ fc_w, const float* __restrict__ fc_b,
        float* __restrict__ hout, float* __restrict__ out, int n) {
    int lane = threadIdx.x & 63;
    int gwid   = (blockIdx.x * blockDim.x + threadIdx.x) >> 6;
    int nwaves = (gridDim.x * blockDim.x) >> 6;
    int r4 = lane >> 4;            // which of 4 edges in a step
    int c4 = lane & 15;            // which float4 of the 64-ch row

    float wl[64], wr[64];
    {
        const float4* pl = reinterpret_cast<const float4*>(w_l + lane * 64);
        const float4* pr = reinterpret_cast<const float4*>(w_r + lane * 64);
        #pragma unroll
        for (int q = 0; q < 16; ++q) {
            float4 a = pl[q], c = pr[q];
            wl[4*q] = a.x; wl[4*q+1] = a.y; wl[4*q+2] = a.z; wl[4*q+3] = a.w;
            wr[4*q] = c.x; wr[4*q+1] = c.y; wr[4*q+2] = c.z; wr[4*q+3] = c.w;
        }
    }
    float bias = bvec[lane];
    float fw0 = 0.f, fw1 = 0.f, fw2 = 0.f;
    if (LAST) { fw0 = fc_w[lane]; fw1 = fc_w[64 + lane]; fw2 = fc_w[128 + lane]; }

    for (int node = gwid; node < n; node += nwaves) {
        int start = row_off[node], end = row_off[node + 1];
        int deg = end - start;
        float4 h4 = *reinterpret_cast<const float4*>(xin + node * 64 + (c4 << 2));
        float ax = 0.f, ay = 0.f, az = 0.f, aw = 0.f;
        for (int base = start; base < end; base += 64) {
            int cnt = min(64, end - base);
            int sid = (lane < cnt) ? src_sorted[base + lane] : 0;
            for (int jj = 0; jj < cnt; jj += 4) {
                int eidx = jj + r4;
                int s = __shfl(sid, eidx);
                const float4 v = *reinterpret_cast<const float4*>(xin + s * 64 + (c4 << 2));
                if (eidx < cnt) { ax += v.x; ay += v.y; az += v.z; aw += v.w; }
            }
        }
        #pragma unroll
        for (int sh = 16; sh <= 32; sh <<= 1) {
            ax += __shfl_xor(ax, sh); ay += __shfl_xor(ay, sh);
            az += __shfl_xor(az, sh); aw += __shfl_xor(aw, sh);
        }
        float rs = 1.0f / (float)max(deg, 1);
        float arrA[4] = {ax * rs, ay * rs, az * rs, aw * rs};
        float arrH[4] = {h4.x, h4.y, h4.z, h4.w};

        // 8 independent fma chains; all indices static after unroll
        float aA[4] = {bias, 0.f, 0.f, 0.f};
        float aH[4] = {0.f, 0.f, 0.f, 0.f};
        #pragma unroll
        for (int k = 0; k < 64; ++k) {
            float a = bcast_lane(arrA[k & 3], k >> 2);
            float h = bcast_lane(arrH[k & 3], k >> 2);
            aA[k & 3] = fmaf(a, wl[k], aA[k & 3]);
            aH[k & 3] = fmaf(h, wr[k], aH[k & 3]);
        }
        float acc = ((aA[0] + aA[1]) + (aA[2] + aA[3]))
                  + ((aH[0] + aH[1]) + (aH[2] + aH[3]));
        float hval = fmaxf(acc, 0.f);

        if (!LAST) {
            hout[node * 64 + lane] = hval;
        } else {
            float p0 = hval * fw0, p1 = hval * fw1, p2 = hval * fw2;
            #pragma unroll
            for (int s = 32; s > 0; s >>= 1) {
                p0 += __shfl_xor(p0, s);
                p1 += __shfl_xor(p1, s);
                p2 += __shfl_xor(p2, s);
            }
            if (lane == 0) {
                out[node * 3 + 0] = p0 + fc_b[0];
                out[node * 3 + 1] = p1 + fc_b[1];
                out[node * 3 + 2] = p2 + fc_b[2];
            }
        }
    }
}

// layer 1: CIN=6. Gather: 8 edges x 8 lanes (6 channels used).
__global__ void __launch_bounds__(256) fused6_kernel(
        const float* __restrict__ xin, const int* __restrict__ row_off,
        const int* __restrict__ src_sorted,
        const float* __restrict__ w_l, const float* __restrict__ bvec,
        const float* __restrict__ w_r,
        float* __restrict__ hout, int n) {
    int lane = threadIdx.x & 63;
    int gwid   = (blockIdx.x * blockDim.x + threadIdx.x) >> 6;
    int nwaves = (gridDim.x * blockDim.x) >> 6;
    int e8 = lane >> 3, c = lane & 7;

    float wl[6], wr[6];
    #pragma unroll
    for (int k = 0; k < 6; ++k) { wl[k] = w_l[lane*6 + k]; wr[k] = w_r[lane*6 + k]; }
    float bias = bvec[lane];

    for (int node = gwid; node < n; node += nwaves) {
        int start = row_off[node], end = row_off[node + 1];
        int deg = end - start;
        float acc = 0.f;
        for (int base = start; base < end; base += 64) {
            int cnt = min(64, end - base);
            int sid = (lane < cnt) ? src_sorted[base + lane] : 0;
            for (int jj = 0; jj < cnt; jj += 8) {
                int eidx = jj + e8;
                int s = __shfl(sid, eidx);
                bool valid = (eidx < cnt) && (c < 6);
                float v = valid ? xin[s * 6 + c] : 0.f;
                acc += v;
            }
        }
        #pragma unroll
        for (int sh = 8; sh <= 32; sh <<= 1) acc += __shfl_xor(acc, sh);
        float rs = 1.0f / (float)max(deg, 1);
        float av = acc * rs;
        float hv = (lane < 6) ? xin[node * 6 + lane] : 0.f;

        float o = bias;
        #pragma unroll
        for (int k = 0; k < 6; ++k) {
            o = fmaf(bcast_lane(av, k), wl[k], fmaf(bcast_lane(hv, k), wr[k], o));
        }
        hout[node * 64 + lane] = fmaxf(o, 0.f);
    }
}

// ---------------- launch ----------------

extern "C" void kernel_launch(void* const* d_in, const int* in_sizes, int n_in,
                              void* d_out, int out_size, void* d_ws, size_t ws_size,
                              hipStream_t stream) {
    const float* x    = (const float*)d_in[0];
    const int*   ei   = (const int*)d_in[1];
    const float* w1_l = (const float*)d_in[2];
    const float* b1   = (const float*)d_in[3];
    const float* w1_r = (const float*)d_in[4];
    const float* w2_l = (const float*)d_in[5];
    const float* b2   = (const float*)d_in[6];
    const float* w2_r = (const float*)d_in[7];
    const float* w3_l = (const float*)d_in[8];
    const float* b3   = (const float*)d_in[9];
    const float* w3_r = (const float*)d_in[10];
    const float* fc_w = (const float*)d_in[11];
    const float* fc_b = (const float*)d_in[12];
    float* out = (float*)d_out;

    const int N = N_NODES;
    const int E = N_EDGES;
    const int* src = ei;
    const int* dst = ei + E;

    size_t off = 0;
    auto alloc = [&](size_t bytes) -> void* {
        void* p = (char*)d_ws + off;
        off += (bytes + 255) & ~size_t(255);
        return p;
    };
    int*      bincur     = (int*)alloc(NB * sizeof(int));
    int*      binbase    = (int*)alloc(NB * sizeof(int));
    unsigned* binned     = (unsigned*)alloc((size_t)NB * CAP * sizeof(unsigned));
    int*      row_off    = (int*)alloc((N + 1) * sizeof(int));
    int*      src_sorted = (int*)alloc((size_t)E * sizeof(int));
    float*    hA         = (float*)alloc((size_t)N * 64 * sizeof(float));
    float*    hB         = (float*)alloc((size_t)N * 64 * sizeof(float));

    hipMemsetAsync(bincur, 0, NB * sizeof(int), stream);

    int nb_fill = (E + CHUNK - 1) / CHUNK;

    binfill_kernel<<<nb_fill, 1024, 0, stream>>>(src, dst, bincur, binned, E);
    binscan_kernel<<<1, 64, 0, stream>>>(bincur, binbase, row_off);
    csrfinal_kernel<<<NB, 256, 0, stream>>>(binned, bincur, binbase, row_off, src_sorted);

    // layer 1 (6 -> 64)
    fused6_kernel<<<2048, 256, 0, stream>>>(x, row_off, src_sorted, w1_l, b1, w1_r, hA, N);
    // layer 2 (64 -> 64)
    fused64_kernel<false><<<1536, 256, 0, stream>>>(hA, row_off, src_sorted, w2_l, b2, w2_r,
                                                    nullptr, nullptr, hB, nullptr, N);
    // layer 3 (64 -> 64) + fused final FC (64 -> 3)
    fused64_kernel<true><<<1536, 256, 0, stream>>>(hB, row_off, src_sorted, w3_l, b3, w3_r,
                                                   fc_w, fc_b, nullptr, out, N);
}

// Round 8
// 332.502 us; speedup vs baseline: 1.2778x; 1.2778x over previous
//
#include <hip/hip_runtime.h>
#include <hip/hip_bf16.h>
#include <hip/hip_fp16.h>

#define N_NODES 100000
#define N_EDGES 1600000
#define NB 391        // bins of 256 dst-nodes
#define CAP 4608      // per-bin capacity: mean 4092, sigma 64 -> +8 sigma
#define CHUNK 8192    // edges per binfill block

__device__ __forceinline__ float bcast_lane(float v, int k) {
    return __int_as_float(__builtin_amdgcn_readlane(__float_as_int(v), k));
}

// ---------------- phase 1: bin edges by dst>>8 ----------------

__global__ void __launch_bounds__(1024) binfill_kernel(
        const int* __restrict__ src, const int* __restrict__ dst,
        int* __restrict__ bincur, unsigned* __restrict__ binned, int e) {
    __shared__ int hcount[NB];
    __shared__ int hloc[NB];
    __shared__ int hbase[NB];
    __shared__ unsigned stage[CHUNK];

    int tid = threadIdx.x;
    int base0 = blockIdx.x * CHUNK;

    for (int i = tid; i < NB; i += 1024) hcount[i] = 0;
    __syncthreads();

    int bq[8]; int rq[8]; unsigned pq[8];
    #pragma unroll
    for (int q = 0; q < 8; ++q) {
        int i = base0 + q * 1024 + tid;
        bq[q] = -1;
        if (i < e) {
            int s = src[i], d = dst[i];
            int b = d >> 8;
            bq[q] = b;
            rq[q] = atomicAdd(&hcount[b], 1);
            pq[q] = ((unsigned)s << 8) | (unsigned)(d & 255);
        }
    }
    __syncthreads();

    if (tid < NB) hbase[tid] = atomicAdd(&bincur[tid], hcount[tid]);

    if (tid < 64) {
        int run = 0;
        for (int seg = 0; seg < NB; seg += 64) {
            int idx = seg + tid;
            int d0 = (idx < NB) ? hcount[idx] : 0;
            int v = d0;
            #pragma unroll
            for (int off = 1; off < 64; off <<= 1) {
                int t = __shfl_up(v, off);
                if (tid >= off) v += t;
            }
            if (idx < NB) hloc[idx] = run + v - d0;
            run += __shfl(v, 63);
        }
    }
    __syncthreads();

    #pragma unroll
    for (int q = 0; q < 8; ++q)
        if (bq[q] >= 0) stage[hloc[bq[q]] + rq[q]] = pq[q];
    __syncthreads();

    int w = tid >> 6, lane = tid & 63;
    for (int b = w; b < NB; b += 16) {
        int len = hcount[b];
        int gb0 = hbase[b];
        int lim = min(len, CAP - gb0);
        int lo = hloc[b];
        unsigned* gp = binned + (long long)b * CAP + gb0;
        for (int j = lane; j < lim; j += 64) gp[j] = stage[lo + j];
    }
}

// ---------------- phase 2: scan bin totals ----------------

__global__ void binscan_kernel(const int* __restrict__ bincur,
                               int* __restrict__ binbase, int* __restrict__ row_off) {
    int lane = threadIdx.x;   // 64 threads
    int run = 0;
    for (int seg = 0; seg < NB; seg += 64) {
        int idx = seg + lane;
        int d = (idx < NB) ? bincur[idx] : 0;
        int v = d;
        #pragma unroll
        for (int off = 1; off < 64; off <<= 1) {
            int t = __shfl_up(v, off);
            if (lane >= off) v += t;
        }
        if (idx < NB) binbase[idx] = run + v - d;
        run += __shfl(v, 63);
    }
    if (lane == 0) row_off[N_NODES] = run;
}

// ---------------- phase 3: per-bin CSR finalize ----------------

__global__ void __launch_bounds__(256) csrfinal_kernel(
        const unsigned* __restrict__ binned, const int* __restrict__ bincur,
        const int* __restrict__ binbase,
        int* __restrict__ row_off, int* __restrict__ src_sorted) {
    __shared__ int cnt[256];
    __shared__ int wsum[4];
    __shared__ unsigned stage[CAP];
    int b = blockIdx.x, tid = threadIdx.x, lane = tid & 63, w = tid >> 6;
    long long boff = (long long)b * CAP;
    int total = min(bincur[b], CAP);
    int base = binbase[b];

    cnt[tid] = 0;
    __syncthreads();
    for (int j = tid; j < total; j += 256) atomicAdd(&cnt[binned[boff + j] & 255u], 1);
    __syncthreads();

    int d = cnt[tid];
    int v = d;
    #pragma unroll
    for (int off = 1; off < 64; off <<= 1) {
        int t = __shfl_up(v, off);
        if (lane >= off) v += t;
    }
    if (lane == 63) wsum[w] = v;
    __syncthreads();
    int woff = 0;
    for (int ww = 0; ww < w; ++ww) woff += wsum[ww];
    int excl = woff + v - d;

    int node = b * 256 + tid;
    if (node < N_NODES) row_off[node] = base + excl;
    __syncthreads();
    cnt[tid] = excl;          // cursor
    __syncthreads();

    for (int j = tid; j < total; j += 256) {
        unsigned p = binned[boff + j];
        int pos = atomicAdd(&cnt[p & 255u], 1);
        stage[pos] = p >> 8;
    }
    __syncthreads();
    for (int j = tid; j < total; j += 256) src_sorted[base + j] = (int)stage[j];
}

// ---------------- fused layer: mean-aggregate + dual matvec + relu ----------
// R6 structure (768 blocks, (256,3), single fma chain) + fp16 gather:
// neighbor rows are read from a 128B-per-row fp16 mirror (halves the
// beyond-L2 traffic that R6 evidence showed is the binding constraint:
// dur 144us == 187MB / 1.3TB/s). Self-term stays fp32. Non-LAST layers
// write both fp32 and fp16 copies of the output.

template <bool LAST>
__global__ void __launch_bounds__(256, 3) fused64_kernel(
        const float* __restrict__ xin,          // fp32 activations (self-term)
        const __half* __restrict__ xg,          // fp16 mirror (gather)
        const int* __restrict__ row_off,
        const int* __restrict__ src_sorted,
        const float* __restrict__ w_l, const float* __restrict__ bvec,
        const float* __restrict__ w_r,
        const float* __restrict__ fc_w, const float* __restrict__ fc_b,
        float* __restrict__ hout, __half* __restrict__ hout16,
        float* __restrict__ out, int n) {
    int lane = threadIdx.x & 63;
    int gwid   = (blockIdx.x * blockDim.x + threadIdx.x) >> 6;
    int nwaves = (gridDim.x * blockDim.x) >> 6;
    int r8 = lane >> 3;            // which of 8 edges in a step
    int c8 = lane & 7;             // which 8-channel slice of the 64-ch row
    int c4 = lane & 15;            // fp32 self-row slice

    float wl[64], wr[64];
    {
        const float4* pl = reinterpret_cast<const float4*>(w_l + lane * 64);
        const float4* pr = reinterpret_cast<const float4*>(w_r + lane * 64);
        #pragma unroll
        for (int q = 0; q < 16; ++q) {
            float4 a = pl[q], c = pr[q];
            wl[4*q] = a.x; wl[4*q+1] = a.y; wl[4*q+2] = a.z; wl[4*q+3] = a.w;
            wr[4*q] = c.x; wr[4*q+1] = c.y; wr[4*q+2] = c.z; wr[4*q+3] = c.w;
        }
    }
    float bias = bvec[lane];
    float fw0 = 0.f, fw1 = 0.f, fw2 = 0.f;
    if (LAST) { fw0 = fc_w[lane]; fw1 = fc_w[64 + lane]; fw2 = fc_w[128 + lane]; }

    for (int node = gwid; node < n; node += nwaves) {
        int start = row_off[node], end = row_off[node + 1];
        int deg = end - start;
        float4 h4 = *reinterpret_cast<const float4*>(xin + node * 64 + (c4 << 2));

        float a[8] = {0.f, 0.f, 0.f, 0.f, 0.f, 0.f, 0.f, 0.f};
        for (int base = start; base < end; base += 64) {
            int cnt = min(64, end - base);
            int sid = (lane < cnt) ? src_sorted[base + lane] : 0;
            for (int jj = 0; jj < cnt; jj += 8) {
                int eidx = jj + r8;
                int s = __shfl(sid, eidx);
                // 16B = 8 fp16 channels; 8 lanes cover one 128B row
                const uint4 v = *reinterpret_cast<const uint4*>(xg + (size_t)s * 64 + (c8 << 3));
                if (eidx < cnt) {
                    const __half2* h2 = reinterpret_cast<const __half2*>(&v);
                    #pragma unroll
                    for (int t = 0; t < 4; ++t) {
                        float2 f = __half22float2(h2[t]);
                        a[2*t]   += f.x;
                        a[2*t+1] += f.y;
                    }
                }
            }
        }
        #pragma unroll
        for (int t = 0; t < 8; ++t) {
            #pragma unroll
            for (int sh = 8; sh <= 32; sh <<= 1) a[t] += __shfl_xor(a[t], sh);
        }
        float rs = 1.0f / (float)max(deg, 1);
        float arrA[8];
        #pragma unroll
        for (int t = 0; t < 8; ++t) arrA[t] = a[t] * rs;
        float arrH[4] = {h4.x, h4.y, h4.z, h4.w};

        float acc = bias;
        #pragma unroll
        for (int k = 0; k < 64; ++k) {
            float av = bcast_lane(arrA[k & 7], k >> 3);   // channel k of agg-mean
            float hv = bcast_lane(arrH[k & 3], k >> 2);   // channel k of self row
            acc = fmaf(av, wl[k], fmaf(hv, wr[k], acc));
        }
        float hval = fmaxf(acc, 0.f);

        if (!LAST) {
            hout[node * 64 + lane] = hval;
            hout16[node * 64 + lane] = __float2half(hval);
        } else {
            float p0 = hval * fw0, p1 = hval * fw1, p2 = hval * fw2;
            #pragma unroll
            for (int s = 32; s > 0; s >>= 1) {
                p0 += __shfl_xor(p0, s);
                p1 += __shfl_xor(p1, s);
                p2 += __shfl_xor(p2, s);
            }
            if (lane == 0) {
                out[node * 3 + 0] = p0 + fc_b[0];
                out[node * 3 + 1] = p1 + fc_b[1];
                out[node * 3 + 2] = p2 + fc_b[2];
            }
        }
    }
}

// layer 1: CIN=6, gathers fp32 x directly (38MB demand, cheap).
__global__ void __launch_bounds__(256) fused6_kernel(
        const float* __restrict__ xin, const int* __restrict__ row_off,
        const int* __restrict__ src_sorted,
        const float* __restrict__ w_l, const float* __restrict__ bvec,
        const float* __restrict__ w_r,
        float* __restrict__ hout, __half* __restrict__ hout16, int n) {
    int lane = threadIdx.x & 63;
    int gwid   = (blockIdx.x * blockDim.x + threadIdx.x) >> 6;
    int nwaves = (gridDim.x * blockDim.x) >> 6;
    int e8 = lane >> 3, c = lane & 7;

    float wl[6], wr[6];
    #pragma unroll
    for (int k = 0; k < 6; ++k) { wl[k] = w_l[lane*6 + k]; wr[k] = w_r[lane*6 + k]; }
    float bias = bvec[lane];

    for (int node = gwid; node < n; node += nwaves) {
        int start = row_off[node], end = row_off[node + 1];
        int deg = end - start;
        float acc = 0.f;
        for (int base = start; base < end; base += 64) {
            int cnt = min(64, end - base);
            int sid = (lane < cnt) ? src_sorted[base + lane] : 0;
            for (int jj = 0; jj < cnt; jj += 8) {
                int eidx = jj + e8;
                int s = __shfl(sid, eidx);
                bool valid = (eidx < cnt) && (c < 6);
                float v = valid ? xin[s * 6 + c] : 0.f;
                acc += v;
            }
        }
        #pragma unroll
        for (int sh = 8; sh <= 32; sh <<= 1) acc += __shfl_xor(acc, sh);
        float rs = 1.0f / (float)max(deg, 1);
        float av = acc * rs;
        float hv = (lane < 6) ? xin[node * 6 + lane] : 0.f;

        float o = bias;
        #pragma unroll
        for (int k = 0; k < 6; ++k) {
            o = fmaf(bcast_lane(av, k), wl[k], fmaf(bcast_lane(hv, k), wr[k], o));
        }
        float hval = fmaxf(o, 0.f);
        hout[node * 64 + lane] = hval;
        hout16[node * 64 + lane] = __float2half(hval);
    }
}

// ---------------- launch ----------------

extern "C" void kernel_launch(void* const* d_in, const int* in_sizes, int n_in,
                              void* d_out, int out_size, void* d_ws, size_t ws_size,
                              hipStream_t stream) {
    const float* x    = (const float*)d_in[0];
    const int*   ei   = (const int*)d_in[1];
    const float* w1_l = (const float*)d_in[2];
    const float* b1   = (const float*)d_in[3];
    const float* w1_r = (const float*)d_in[4];
    const float* w2_l = (const float*)d_in[5];
    const float* b2   = (const float*)d_in[6];
    const float* w2_r = (const float*)d_in[7];
    const float* w3_l = (const float*)d_in[8];
    const float* b3   = (const float*)d_in[9];
    const float* w3_r = (const float*)d_in[10];
    const float* fc_w = (const float*)d_in[11];
    const float* fc_b = (const float*)d_in[12];
    float* out = (float*)d_out;

    const int N = N_NODES;
    const int E = N_EDGES;
    const int* src = ei;
    const int* dst = ei + E;

    size_t off = 0;
    auto alloc = [&](size_t bytes) -> void* {
        void* p = (char*)d_ws + off;
        off += (bytes + 255) & ~size_t(255);
        return p;
    };
    int*      bincur     = (int*)alloc(NB * sizeof(int));
    int*      binbase    = (int*)alloc(NB * sizeof(int));
    unsigned* binned     = (unsigned*)alloc((size_t)NB * CAP * sizeof(unsigned));
    int*      row_off    = (int*)alloc((N + 1) * sizeof(int));
    int*      src_sorted = (int*)alloc((size_t)E * sizeof(int));
    float*    hA         = (float*)alloc((size_t)N * 64 * sizeof(float));
    float*    hB         = (float*)alloc((size_t)N * 64 * sizeof(float));
    __half*   hA16       = (__half*)alloc((size_t)N * 64 * sizeof(__half));
    __half*   hB16       = (__half*)alloc((size_t)N * 64 * sizeof(__half));

    hipMemsetAsync(bincur, 0, NB * sizeof(int), stream);

    int nb_fill = (E + CHUNK - 1) / CHUNK;

    binfill_kernel<<<nb_fill, 1024, 0, stream>>>(src, dst, bincur, binned, E);
    binscan_kernel<<<1, 64, 0, stream>>>(bincur, binbase, row_off);
    csrfinal_kernel<<<NB, 256, 0, stream>>>(binned, bincur, binbase, row_off, src_sorted);

    // layer 1 (6 -> 64)
    fused6_kernel<<<2048, 256, 0, stream>>>(x, row_off, src_sorted, w1_l, b1, w1_r,
                                            hA, hA16, N);
    // layer 2 (64 -> 64)
    fused64_kernel<false><<<768, 256, 0, stream>>>(hA, hA16, row_off, src_sorted,
                                                   w2_l, b2, w2_r,
                                                   nullptr, nullptr, hB, hB16, nullptr, N);
    // layer 3 (64 -> 64) + fused final FC (64 -> 3)
    fused64_kernel<true><<<768, 256, 0, stream>>>(hB, hB16, row_off, src_sorted,
                                                  w3_l, b3, w3_r,
                                                  fc_w, fc_b, nullptr, nullptr, out, N);
}